// Round 1
// baseline (216.864 us; speedup 1.0000x reference)
//
#include <hip/hip_runtime.h>
#include <math.h>

#define NATOMS 8192
#define NF 128
#define NH 64
#define NB 8
#define BI 128      // atoms per i-tile == threads per pair-block
#define SLICES 16   // j-slices per i-tile

// workspace byte offsets
#define OFF_BATCH32 0         // int[NATOMS]     32 KB
#define OFF_Q       32768     // float[NATOMS]   32 KB
#define OFF_ACCQ    65536     // float[NATOMS]   32 KB
#define OFF_GSUM    98304     // float[NB]
#define OFF_GSTART  98368     // int[NB+1]

// ---------------------------------------------------------------------------
// prep: detect batch int width, convert to int32, zero gsum, graph boundaries
// ---------------------------------------------------------------------------
__global__ void prep_kernel(const void* batch_raw, int* batch32,
                            float* gsum, int* gstart) {
    __shared__ int flag;
    const int tid = threadIdx.x;
    if (tid == 0) flag = 0;
    __syncthreads();

    const int* v32 = (const int*)batch_raw;
    int dec = 0;
    for (int i = tid; i < NATOMS - 1; i += blockDim.x)
        if (v32[i + 1] < v32[i]) dec = 1;      // sorted int32 never decreases
    if (dec) flag = 1;
    __syncthreads();

    const bool is64 = (flag != 0);
    const long long* v64 = (const long long*)batch_raw;
    for (int i = tid; i < NATOMS; i += blockDim.x)
        batch32[i] = is64 ? (int)v64[i] : v32[i];
    if (tid < NB) gsum[tid] = 0.0f;
    __syncthreads();

    if (tid <= NB) {
        if (tid == NB) {
            gstart[NB] = NATOMS;
        } else {
            int lo = 0, hi = NATOMS;            // lower_bound(batch32, tid)
            while (lo < hi) {
                int mid = (lo + hi) >> 1;
                if (batch32[mid] < tid) lo = mid + 1; else hi = mid;
            }
            gstart[tid] = lo;
        }
    }
}

// ---------------------------------------------------------------------------
// q: one wave per atom; lane k owns hidden unit k. Also zeroes accq.
// ---------------------------------------------------------------------------
__global__ __launch_bounds__(256) void q_kernel(
    const float* __restrict__ x, const float* __restrict__ W1,
    const float* __restrict__ b1, const float* __restrict__ W2,
    const float* __restrict__ b2, const int* __restrict__ batch32,
    float* __restrict__ q, float* gsum, float* __restrict__ accq) {
    const int gt = blockIdx.x * blockDim.x + threadIdx.x;
    if (gt < NATOMS) accq[gt] = 0.0f;           // zero pair accumulator

    const int atom = gt >> 6;                   // wave id == atom
    const int lane = threadIdx.x & 63;
    if (atom >= NATOMS) return;

    const float* xr = x + atom * NF;
    float z = b1[lane];
#pragma unroll
    for (int f0 = 0; f0 < NF; f0 += 4) {
        const float4 xv = *(const float4*)(xr + f0);
        z = fmaf(xv.x, W1[(f0 + 0) * NH + lane], z);
        z = fmaf(xv.y, W1[(f0 + 1) * NH + lane], z);
        z = fmaf(xv.z, W1[(f0 + 2) * NH + lane], z);
        z = fmaf(xv.w, W1[(f0 + 3) * NH + lane], z);
    }
    const float h = z / (1.0f + __expf(-z));    // SiLU
    float t = h * W2[lane];
#pragma unroll
    for (int m = 32; m >= 1; m >>= 1) t += __shfl_xor(t, m, 64);
    if (lane == 0) {
        const float qv = t + b2[0];
        q[atom] = qv;
        atomicAdd(&gsum[batch32[atom]], qv);
    }
}

// ---------------------------------------------------------------------------
// pair: grid (NATOMS/BI, SLICES). Thread = one atom i; LDS j-tiles of
// (pos.xyz, neutralized q). Self term included, subtracted in finalize.
// ---------------------------------------------------------------------------
__global__ __launch_bounds__(BI) void pair_kernel(
    const float* __restrict__ pos, const float* __restrict__ q,
    const int* __restrict__ batch32, const int* __restrict__ gstart,
    const float* __restrict__ gsum, float* accq,
    const float* __restrict__ scr_p, const float* __restrict__ soft_p) {
    __shared__ float4 tile[BI];
    __shared__ float smean[NB];

    const int tid = threadIdx.x;
    if (tid < NB) {
        const int c = gstart[tid + 1] - gstart[tid];
        smean[tid] = gsum[tid] / (float)(c > 0 ? c : 1);
    }
    __syncthreads();

    const float scr = *scr_p;
    const float soft = *soft_p;
    const float soft2 = soft * soft;

    const int i = blockIdx.x * BI + tid;
    const int gi = batch32[i];
    const int si = gstart[gi];
    const unsigned span = (unsigned)(gstart[gi + 1] - si);
    const float pix = pos[3 * i + 0];
    const float piy = pos[3 * i + 1];
    const float piz = pos[3 * i + 2];

    // block-wide j range = union of graph ranges of this i-tile
    const int i0 = blockIdx.x * BI;
    const int jlo = gstart[batch32[i0]];
    const int jhi = gstart[batch32[i0 + BI - 1] + 1];
    const int per = (jhi - jlo + SLICES - 1) / SLICES;
    const int js = jlo + (int)blockIdx.y * per;
    const int je = min(js + per, jhi);

    float acc = 0.0f;
    for (int jt = js; jt < je; jt += BI) {
        __syncthreads();
        const int jj = jt + tid;
        float4 v;
        if (jj < je) {
            v.x = pos[3 * jj + 0];
            v.y = pos[3 * jj + 1];
            v.z = pos[3 * jj + 2];
            v.w = q[jj] - smean[batch32[jj]];
        } else {
            v.x = v.y = v.z = v.w = 0.0f;
        }
        tile[tid] = v;
        __syncthreads();

        const int cnt = min(BI, je - jt);       // uniform across block
        for (int u = 0; u < cnt; ++u) {
            const float4 p = tile[u];
            const float dx = p.x - pix;
            const float dy = p.y - piy;
            const float dz = p.z - piz;
            float d2 = fmaf(dx, dx, soft2);
            d2 = fmaf(dy, dy, d2);
            d2 = fmaf(dz, dz, d2);
            const float rinv = rsqrtf(d2);
            const float r = d2 * rinv;
            const float e = __expf(-scr * r);
            const int j = jt + u;
            const float w = ((unsigned)(j - si) < span) ? p.w : 0.0f;
            acc = fmaf(w * e, rinv, acc);
        }
    }
    atomicAdd(&accq[i], acc);
}

// ---------------------------------------------------------------------------
// finalize: out[i] = 0.5 * qn_i * (accq[i] - qn_i * selfkern)
// ---------------------------------------------------------------------------
__global__ void fin_kernel(const float* __restrict__ q,
                           const int* __restrict__ batch32,
                           const float* __restrict__ gsum,
                           const int* __restrict__ gstart,
                           const float* __restrict__ accq,
                           float* __restrict__ out,
                           const float* __restrict__ scr_p,
                           const float* __restrict__ soft_p) {
    const int i = blockIdx.x * blockDim.x + threadIdx.x;
    if (i >= NATOMS) return;
    const int g = batch32[i];
    const int c = gstart[g + 1] - gstart[g];
    const float mean = gsum[g] / (float)(c > 0 ? c : 1);
    const float qn = q[i] - mean;
    const float sa = fabsf(*soft_p);
    const float selfk = __expf(-(*scr_p) * sa) / sa;
    out[i] = 0.5f * qn * (accq[i] - qn * selfk);
}

extern "C" void kernel_launch(void* const* d_in, const int* in_sizes, int n_in,
                              void* d_out, int out_size, void* d_ws, size_t ws_size,
                              hipStream_t stream) {
    const float* x    = (const float*)d_in[0];
    const float* pos  = (const float*)d_in[1];
    // d_in[2] = cell (unused by reference math for nonperiodic path)
    const float* W1   = (const float*)d_in[3];
    const float* b1   = (const float*)d_in[4];
    const float* W2   = (const float*)d_in[5];
    const float* b2   = (const float*)d_in[6];
    const float* scr  = (const float*)d_in[7];
    const float* soft = (const float*)d_in[8];
    const void*  braw = (const void*)d_in[9];

    char* ws = (char*)d_ws;
    int*   batch32 = (int*)(ws + OFF_BATCH32);
    float* q       = (float*)(ws + OFF_Q);
    float* accq    = (float*)(ws + OFF_ACCQ);
    float* gsum    = (float*)(ws + OFF_GSUM);
    int*   gstart  = (int*)(ws + OFF_GSTART);
    float* out     = (float*)d_out;

    prep_kernel<<<1, 256, 0, stream>>>(braw, batch32, gsum, gstart);
    q_kernel<<<NATOMS / 4, 256, 0, stream>>>(x, W1, b1, W2, b2, batch32,
                                             q, gsum, accq);
    dim3 pgrid(NATOMS / BI, SLICES);
    pair_kernel<<<pgrid, BI, 0, stream>>>(pos, q, batch32, gstart, gsum,
                                          accq, scr, soft);
    fin_kernel<<<NATOMS / 256, 256, 0, stream>>>(q, batch32, gsum, gstart,
                                                 accq, out, scr, soft);
}

// Round 2
// 125.047 us; speedup vs baseline: 1.7343x; 1.7343x over previous
//
#include <hip/hip_runtime.h>
#include <math.h>

#define NATOMS 8192
#define NF 128
#define NH 64
#define NB 8
#define BI 128      // atoms per i-tile == threads per pair-block
#define SLICES 32   // j-slices per i-tile

// workspace byte offsets
#define OFF_BATCH32 0         // int[NATOMS]     32 KB
#define OFF_Q       32768     // float[NATOMS]   32 KB
#define OFF_ACCQ    65536     // float[NATOMS]   32 KB
#define OFF_GSUM    98304     // float[NB]
#define OFF_GSTART  98368     // int[NB+1]

// ---------------------------------------------------------------------------
// prep: detect batch int width, convert to int32, graph boundaries
// ---------------------------------------------------------------------------
__global__ void prep_kernel(const void* batch_raw, int* batch32, int* gstart) {
    __shared__ int flag;
    const int tid = threadIdx.x;
    if (tid == 0) flag = 0;
    __syncthreads();

    const int* v32 = (const int*)batch_raw;
    int dec = 0;
    for (int i = tid; i < NATOMS - 1; i += blockDim.x)
        if (v32[i + 1] < v32[i]) dec = 1;      // sorted int32 never decreases
    if (dec) flag = 1;
    __syncthreads();

    const bool is64 = (flag != 0);
    const long long* v64 = (const long long*)batch_raw;
    for (int i = tid; i < NATOMS; i += blockDim.x)
        batch32[i] = is64 ? (int)v64[i] : v32[i];
    __syncthreads();

    if (tid <= NB) {
        if (tid == NB) {
            gstart[NB] = NATOMS;
        } else {
            int lo = 0, hi = NATOMS;            // lower_bound(batch32, tid)
            while (lo < hi) {
                int mid = (lo + hi) >> 1;
                if (batch32[mid] < tid) lo = mid + 1; else hi = mid;
            }
            gstart[tid] = lo;
        }
    }
}

// ---------------------------------------------------------------------------
// q: one wave per atom; lane k owns hidden unit k. Also zeroes accq.
// NO atomics (the R0 version spent 107us serializing 8192 atomics on 8 addrs).
// ---------------------------------------------------------------------------
__global__ __launch_bounds__(256) void q_kernel(
    const float* __restrict__ x, const float* __restrict__ W1,
    const float* __restrict__ b1, const float* __restrict__ W2,
    const float* __restrict__ b2,
    float* __restrict__ q, float* __restrict__ accq) {
    const int gt = blockIdx.x * blockDim.x + threadIdx.x;
    if (gt < NATOMS) accq[gt] = 0.0f;           // zero pair accumulator

    const int atom = gt >> 6;                   // wave id == atom
    const int lane = threadIdx.x & 63;
    if (atom >= NATOMS) return;

    const float* xr = x + atom * NF;
    float z = b1[lane];
#pragma unroll
    for (int f0 = 0; f0 < NF; f0 += 4) {
        const float4 xv = *(const float4*)(xr + f0);
        z = fmaf(xv.x, W1[(f0 + 0) * NH + lane], z);
        z = fmaf(xv.y, W1[(f0 + 1) * NH + lane], z);
        z = fmaf(xv.z, W1[(f0 + 2) * NH + lane], z);
        z = fmaf(xv.w, W1[(f0 + 3) * NH + lane], z);
    }
    const float h = z / (1.0f + __expf(-z));    // SiLU
    float t = h * W2[lane];
#pragma unroll
    for (int m = 32; m >= 1; m >>= 1) t += __shfl_xor(t, m, 64);
    if (lane == 0) q[atom] = t + b2[0];
}

// ---------------------------------------------------------------------------
// gsum: one block per graph; contiguous-range reduction (batch is sorted).
// ---------------------------------------------------------------------------
__global__ __launch_bounds__(256) void gsum_kernel(
    const float* __restrict__ q, const int* __restrict__ gstart,
    float* __restrict__ gsum) {
    __shared__ float part[4];
    const int g = blockIdx.x;
    const int s = gstart[g], e = gstart[g + 1];
    float t = 0.0f;
    for (int i = s + threadIdx.x; i < e; i += 256) t += q[i];
#pragma unroll
    for (int m = 32; m >= 1; m >>= 1) t += __shfl_xor(t, m, 64);
    if ((threadIdx.x & 63) == 0) part[threadIdx.x >> 6] = t;
    __syncthreads();
    if (threadIdx.x == 0) gsum[g] = part[0] + part[1] + part[2] + part[3];
}

// ---------------------------------------------------------------------------
// pair: grid (NATOMS/BI, SLICES). Thread = one atom i; LDS j-tiles of
// (pos.xyz, neutralized q). Self term included, subtracted in finalize.
// ---------------------------------------------------------------------------
__global__ __launch_bounds__(BI) void pair_kernel(
    const float* __restrict__ pos, const float* __restrict__ q,
    const int* __restrict__ batch32, const int* __restrict__ gstart,
    const float* __restrict__ gsum, float* accq,
    const float* __restrict__ scr_p, const float* __restrict__ soft_p) {
    __shared__ float4 tile[BI];
    __shared__ float smean[NB];

    const int tid = threadIdx.x;
    if (tid < NB) {
        const int c = gstart[tid + 1] - gstart[tid];
        smean[tid] = gsum[tid] / (float)(c > 0 ? c : 1);
    }
    __syncthreads();

    const float scr = *scr_p;
    const float soft = *soft_p;
    const float soft2 = soft * soft;

    const int i = blockIdx.x * BI + tid;
    const int gi = batch32[i];
    const int si = gstart[gi];
    const unsigned span = (unsigned)(gstart[gi + 1] - si);
    const float pix = pos[3 * i + 0];
    const float piy = pos[3 * i + 1];
    const float piz = pos[3 * i + 2];

    // block-wide j range = union of graph ranges of this i-tile
    const int i0 = blockIdx.x * BI;
    const int jlo = gstart[batch32[i0]];
    const int jhi = gstart[batch32[i0 + BI - 1] + 1];
    const int per = (jhi - jlo + SLICES - 1) / SLICES;
    const int js = jlo + (int)blockIdx.y * per;
    const int je = min(js + per, jhi);

    float acc = 0.0f;
    for (int jt = js; jt < je; jt += BI) {
        __syncthreads();
        const int jj = jt + tid;
        float4 v;
        if (jj < je) {
            v.x = pos[3 * jj + 0];
            v.y = pos[3 * jj + 1];
            v.z = pos[3 * jj + 2];
            v.w = q[jj] - smean[batch32[jj]];
        } else {
            v.x = v.y = v.z = v.w = 0.0f;
        }
        tile[tid] = v;
        __syncthreads();

        const int cnt = min(BI, je - jt);       // uniform across block
        for (int u = 0; u < cnt; ++u) {
            const float4 p = tile[u];
            const float dx = p.x - pix;
            const float dy = p.y - piy;
            const float dz = p.z - piz;
            float d2 = fmaf(dx, dx, soft2);
            d2 = fmaf(dy, dy, d2);
            d2 = fmaf(dz, dz, d2);
            const float rinv = rsqrtf(d2);
            const float r = d2 * rinv;
            const float e = __expf(-scr * r);
            const int j = jt + u;
            const float w = ((unsigned)(j - si) < span) ? p.w : 0.0f;
            acc = fmaf(w * e, rinv, acc);
        }
    }
    atomicAdd(&accq[i], acc);
}

// ---------------------------------------------------------------------------
// finalize: out[i] = 0.5 * qn_i * (accq[i] - qn_i * selfkern)
// ---------------------------------------------------------------------------
__global__ void fin_kernel(const float* __restrict__ q,
                           const int* __restrict__ batch32,
                           const float* __restrict__ gsum,
                           const int* __restrict__ gstart,
                           const float* __restrict__ accq,
                           float* __restrict__ out,
                           const float* __restrict__ scr_p,
                           const float* __restrict__ soft_p) {
    const int i = blockIdx.x * blockDim.x + threadIdx.x;
    if (i >= NATOMS) return;
    const int g = batch32[i];
    const int c = gstart[g + 1] - gstart[g];
    const float mean = gsum[g] / (float)(c > 0 ? c : 1);
    const float qn = q[i] - mean;
    const float sa = fabsf(*soft_p);
    const float selfk = __expf(-(*scr_p) * sa) / sa;
    out[i] = 0.5f * qn * (accq[i] - qn * selfk);
}

extern "C" void kernel_launch(void* const* d_in, const int* in_sizes, int n_in,
                              void* d_out, int out_size, void* d_ws, size_t ws_size,
                              hipStream_t stream) {
    const float* x    = (const float*)d_in[0];
    const float* pos  = (const float*)d_in[1];
    // d_in[2] = cell (unused by reference math for nonperiodic path)
    const float* W1   = (const float*)d_in[3];
    const float* b1   = (const float*)d_in[4];
    const float* W2   = (const float*)d_in[5];
    const float* b2   = (const float*)d_in[6];
    const float* scr  = (const float*)d_in[7];
    const float* soft = (const float*)d_in[8];
    const void*  braw = (const void*)d_in[9];

    char* ws = (char*)d_ws;
    int*   batch32 = (int*)(ws + OFF_BATCH32);
    float* q       = (float*)(ws + OFF_Q);
    float* accq    = (float*)(ws + OFF_ACCQ);
    float* gsum    = (float*)(ws + OFF_GSUM);
    int*   gstart  = (int*)(ws + OFF_GSTART);
    float* out     = (float*)d_out;

    prep_kernel<<<1, 256, 0, stream>>>(braw, batch32, gstart);
    q_kernel<<<NATOMS / 4, 256, 0, stream>>>(x, W1, b1, W2, b2, q, accq);
    gsum_kernel<<<NB, 256, 0, stream>>>(q, gstart, gsum);
    dim3 pgrid(NATOMS / BI, SLICES);
    pair_kernel<<<pgrid, BI, 0, stream>>>(pos, q, batch32, gstart, gsum,
                                          accq, scr, soft);
    fin_kernel<<<NATOMS / 256, 256, 0, stream>>>(q, batch32, gsum, gstart,
                                                 accq, out, scr, soft);
}

// Round 3
// 120.146 us; speedup vs baseline: 1.8050x; 1.0408x over previous
//
#include <hip/hip_runtime.h>
#include <math.h>

#define NATOMS 8192
#define NF 128
#define NH 64
#define NB 8

#define TI 32       // i-atoms per pairfin block
#define TJ 256      // j-tile size (LDS)
#define JS 8        // j-slices per block (TI*JS = 256 threads)

// workspace byte offsets
#define OFF_BATCH32 0         // int[NATOMS]     32 KB
#define OFF_Q       32768     // float[NATOMS]   32 KB
#define OFF_GSUM    65536     // float[NB]
#define OFF_GSTART  65600     // int[NB+1]

// ---------------------------------------------------------------------------
// fused1: blocks 0..2047 -> q (one wave per atom) + batch32 conversion;
//         block 2048     -> gstart binary searches on the raw batch buffer.
// Width detect: sorted non-negative batch => last int32 word is the max value
// (int32 layout) or the high half of the last int64 (==0). All-zero batch is
// width-invariant, so v32[N-1]==0 <=> treat as int64.
// ---------------------------------------------------------------------------
__global__ __launch_bounds__(256) void fused1_kernel(
    const float* __restrict__ x, const float* __restrict__ W1,
    const float* __restrict__ b1, const float* __restrict__ W2,
    const float* __restrict__ b2, const void* __restrict__ batch_raw,
    int* __restrict__ batch32, int* __restrict__ gstart,
    float* __restrict__ q) {
    const int* v32 = (const int*)batch_raw;
    const long long* v64 = (const long long*)batch_raw;
    const int tid = threadIdx.x;

    if (blockIdx.x == 2048) {                   // gstart block
        const bool is64 = (v32[NATOMS - 1] == 0);
        if (tid <= NB) {
            if (tid == NB) {
                gstart[NB] = NATOMS;
            } else {
                int lo = 0, hi = NATOMS;        // lower_bound(batch, tid)
                while (lo < hi) {
                    int mid = (lo + hi) >> 1;
                    int v = is64 ? (int)v64[mid] : v32[mid];
                    if (v < tid) lo = mid + 1; else hi = mid;
                }
                gstart[tid] = lo;
            }
        }
        return;
    }

    const int gt = blockIdx.x * 256 + tid;
    if (gt < NATOMS) {                          // batch32 conversion
        const bool is64 = (v32[NATOMS - 1] == 0);
        batch32[gt] = is64 ? (int)v64[gt] : v32[gt];
    }

    const int atom = gt >> 6;                   // global wave id == atom
    const int lane = tid & 63;

    const float* xr = x + atom * NF;
    float z = b1[lane];
#pragma unroll
    for (int f0 = 0; f0 < NF; f0 += 4) {
        const float4 xv = *(const float4*)(xr + f0);
        z = fmaf(xv.x, W1[(f0 + 0) * NH + lane], z);
        z = fmaf(xv.y, W1[(f0 + 1) * NH + lane], z);
        z = fmaf(xv.z, W1[(f0 + 2) * NH + lane], z);
        z = fmaf(xv.w, W1[(f0 + 3) * NH + lane], z);
    }
    const float h = z / (1.0f + __expf(-z));    // SiLU
    float t = h * W2[lane];
#pragma unroll
    for (int m = 32; m >= 1; m >>= 1) t += __shfl_xor(t, m, 64);
    if (lane == 0) q[atom] = t + b2[0];
}

// ---------------------------------------------------------------------------
// gsum: one block per graph; contiguous-range reduction (batch is sorted).
// ---------------------------------------------------------------------------
__global__ __launch_bounds__(256) void gsum_kernel(
    const float* __restrict__ q, const int* __restrict__ gstart,
    float* __restrict__ gsum) {
    __shared__ float part[4];
    const int g = blockIdx.x;
    const int s = gstart[g], e = gstart[g + 1];
    float t = 0.0f;
    for (int i = s + threadIdx.x; i < e; i += 256) t += q[i];
#pragma unroll
    for (int m = 32; m >= 1; m >>= 1) t += __shfl_xor(t, m, 64);
    if ((threadIdx.x & 63) == 0) part[threadIdx.x >> 6] = t;
    __syncthreads();
    if (threadIdx.x == 0) gsum[g] = part[0] + part[1] + part[2] + part[3];
}

// ---------------------------------------------------------------------------
// pairfin: 256 blocks x 256 thr = TI(32) i-atoms x JS(8) j-slices.
// LDS j-tiles (pos.xyz, neutralized q); self term included then subtracted
// analytically in the epilogue; no atomics, writes out[] directly.
// ---------------------------------------------------------------------------
__global__ __launch_bounds__(256) void pairfin_kernel(
    const float* __restrict__ pos, const float* __restrict__ q,
    const int* __restrict__ batch32, const int* __restrict__ gstart,
    const float* __restrict__ gsum, float* __restrict__ out,
    const float* __restrict__ scr_p, const float* __restrict__ soft_p) {
    __shared__ float4 tile[TJ];
    __shared__ float smean[NB];
    __shared__ float psum[JS * TI];

    const int tid = threadIdx.x;
    const int ii = tid & (TI - 1);
    const int js = tid >> 5;                    // log2(TI) = 5

    if (tid < NB) {
        const int c = gstart[tid + 1] - gstart[tid];
        smean[tid] = gsum[tid] / (float)(c > 0 ? c : 1);
    }
    __syncthreads();

    const float scr = *scr_p;
    const float soft = *soft_p;
    const float soft2 = soft * soft;

    const int i0 = blockIdx.x * TI;
    const int i = i0 + ii;
    const int gi = batch32[i];
    const int si = gstart[gi];
    const unsigned span = (unsigned)(gstart[gi + 1] - si);
    const float pix = pos[3 * i + 0];
    const float piy = pos[3 * i + 1];
    const float piz = pos[3 * i + 2];

    const int jlo = gstart[batch32[i0]];
    const int jhi = gstart[batch32[i0 + TI - 1] + 1];

    float acc = 0.0f;
    for (int jt = jlo; jt < jhi; jt += TJ) {
        __syncthreads();
        const int jj = jt + tid;
        float4 v;
        if (jj < jhi) {
            v.x = pos[3 * jj + 0];
            v.y = pos[3 * jj + 1];
            v.z = pos[3 * jj + 2];
            v.w = q[jj] - smean[batch32[jj]];
        } else {
            v.x = v.y = v.z = v.w = 0.0f;
        }
        tile[tid] = v;
        __syncthreads();

        const int cnt = min(TJ, jhi - jt);
        const int ue = min(js * 32 + 32, cnt);
        for (int u = js * 32; u < ue; ++u) {
            const float4 p = tile[u];
            const float dx = p.x - pix;
            const float dy = p.y - piy;
            const float dz = p.z - piz;
            float d2 = fmaf(dx, dx, soft2);
            d2 = fmaf(dy, dy, d2);
            d2 = fmaf(dz, dz, d2);
            const float rinv = rsqrtf(d2);
            const float r = d2 * rinv;
            const float e = __expf(-scr * r);
            const int j = jt + u;
            const float w = ((unsigned)(j - si) < span) ? p.w : 0.0f;
            acc = fmaf(w * e, rinv, acc);
        }
    }
    psum[js * TI + ii] = acc;
    __syncthreads();

    if (tid < TI) {
        float tot = 0.0f;
#pragma unroll
        for (int k = 0; k < JS; ++k) tot += psum[k * TI + tid];
        const float mean = smean[gi];           // gi valid: tid<TI => ii==tid
        const float qn = q[i] - mean;
        const float sa = fabsf(soft);
        const float selfk = __expf(-scr * sa) / sa;
        out[i] = 0.5f * qn * (tot - qn * selfk);
    }
}

extern "C" void kernel_launch(void* const* d_in, const int* in_sizes, int n_in,
                              void* d_out, int out_size, void* d_ws, size_t ws_size,
                              hipStream_t stream) {
    const float* x    = (const float*)d_in[0];
    const float* pos  = (const float*)d_in[1];
    // d_in[2] = cell (unused by reference math for nonperiodic path)
    const float* W1   = (const float*)d_in[3];
    const float* b1   = (const float*)d_in[4];
    const float* W2   = (const float*)d_in[5];
    const float* b2   = (const float*)d_in[6];
    const float* scr  = (const float*)d_in[7];
    const float* soft = (const float*)d_in[8];
    const void*  braw = (const void*)d_in[9];

    char* ws = (char*)d_ws;
    int*   batch32 = (int*)(ws + OFF_BATCH32);
    float* q       = (float*)(ws + OFF_Q);
    float* gsum    = (float*)(ws + OFF_GSUM);
    int*   gstart  = (int*)(ws + OFF_GSTART);
    float* out     = (float*)d_out;

    fused1_kernel<<<2049, 256, 0, stream>>>(x, W1, b1, W2, b2, braw,
                                            batch32, gstart, q);
    gsum_kernel<<<NB, 256, 0, stream>>>(q, gstart, gsum);
    pairfin_kernel<<<NATOMS / TI, 256, 0, stream>>>(pos, q, batch32, gstart,
                                                    gsum, out, scr, soft);
}

// Round 5
// 106.415 us; speedup vs baseline: 2.0379x; 1.1290x over previous
//
#include <hip/hip_runtime.h>
#include <math.h>

#define NATOMS 8192
#define NF 128
#define NH 64
#define NB 8

#define TI 16       // i-atoms per pairfin block
#define TJ 256      // j-tile size (LDS)
#define JS 16       // j-slices per block (TI*JS = 256 threads)

// workspace byte offsets
#define OFF_BATCH32 0         // int[NATOMS]     32 KB
#define OFF_Q       32768     // float[NATOMS]   32 KB
#define OFF_GSTART  65536     // int[NB+1]

// ---------------------------------------------------------------------------
// fused1: blocks 0..2047 -> q (one wave per atom) + batch32 conversion;
//         block 2048     -> gstart binary searches on the raw batch buffer.
// Width detect: sorted non-negative batch => v32[N-1]==0 <=> int64 layout.
// ---------------------------------------------------------------------------
__global__ __launch_bounds__(256) void fused1_kernel(
    const float* __restrict__ x, const float* __restrict__ W1,
    const float* __restrict__ b1, const float* __restrict__ W2,
    const float* __restrict__ b2, const void* __restrict__ batch_raw,
    int* __restrict__ batch32, int* __restrict__ gstart,
    float* __restrict__ q) {
    const int* v32 = (const int*)batch_raw;
    const long long* v64 = (const long long*)batch_raw;
    const int tid = threadIdx.x;

    if (blockIdx.x == 2048) {                   // gstart block
        const bool is64 = (v32[NATOMS - 1] == 0);
        if (tid <= NB) {
            if (tid == NB) {
                gstart[NB] = NATOMS;
            } else {
                int lo = 0, hi = NATOMS;        // lower_bound(batch, tid)
                while (lo < hi) {
                    int mid = (lo + hi) >> 1;
                    int v = is64 ? (int)v64[mid] : v32[mid];
                    if (v < tid) lo = mid + 1; else hi = mid;
                }
                gstart[tid] = lo;
            }
        }
        return;
    }

    const int gt = blockIdx.x * 256 + tid;
    if (gt < NATOMS) {                          // batch32 conversion (GUARDED:
        const bool is64 = (v32[NATOMS - 1] == 0);  // gt spans all waves, not atoms)
        batch32[gt] = is64 ? (int)v64[gt] : v32[gt];
    }

    const int atom = gt >> 6;                   // global wave id == atom
    const int lane = tid & 63;

    const float* xr = x + atom * NF;
    float z0 = b1[lane], z1 = 0.0f;             // 2 chains: halve dep latency
#pragma unroll
    for (int f0 = 0; f0 < NF; f0 += 8) {
        const float4 xa = *(const float4*)(xr + f0);
        const float4 xb = *(const float4*)(xr + f0 + 4);
        z0 = fmaf(xa.x, W1[(f0 + 0) * NH + lane], z0);
        z1 = fmaf(xa.y, W1[(f0 + 1) * NH + lane], z1);
        z0 = fmaf(xa.z, W1[(f0 + 2) * NH + lane], z0);
        z1 = fmaf(xa.w, W1[(f0 + 3) * NH + lane], z1);
        z0 = fmaf(xb.x, W1[(f0 + 4) * NH + lane], z0);
        z1 = fmaf(xb.y, W1[(f0 + 5) * NH + lane], z1);
        z0 = fmaf(xb.z, W1[(f0 + 6) * NH + lane], z0);
        z1 = fmaf(xb.w, W1[(f0 + 7) * NH + lane], z1);
    }
    const float z = z0 + z1;
    const float h = z / (1.0f + __expf(-z));    // SiLU
    float t = h * W2[lane];
#pragma unroll
    for (int m = 32; m >= 1; m >>= 1) t += __shfl_xor(t, m, 64);
    if (lane == 0) q[atom] = t + b2[0];
}

// ---------------------------------------------------------------------------
// pairfin: 512 blocks x 256 thr = TI(16) i-atoms x JS(16) j-slices.
// Preamble: per-block graph-sum reduction (batch sorted => contiguous spans)
// replaces the separate gsum kernel. LDS j-tiles hold (pos.xyz, qn). Self
// term included then subtracted analytically; no atomics; writes out[].
// ---------------------------------------------------------------------------
__global__ __launch_bounds__(256) void pairfin_kernel(
    const float* __restrict__ pos, const float* __restrict__ q,
    const int* __restrict__ batch32, const int* __restrict__ gstart,
    float* __restrict__ out,
    const float* __restrict__ scr_p, const float* __restrict__ soft_p) {
    __shared__ float4 tile[TJ];
    __shared__ float smean[NB];
    __shared__ float red[4];
    __shared__ float psum[JS * TI];

    const int tid = threadIdx.x;
    const int ii = tid & (TI - 1);
    const int js = tid >> 4;                    // log2(TI) = 4

    const int i0 = blockIdx.x * TI;
    const int gfirst = batch32[i0];
    const int glast = batch32[i0 + TI - 1];

    // per-block graph mean(s): reduce q over each contiguous graph span
    for (int g = gfirst; g <= glast; ++g) {
        const int s = gstart[g], e = gstart[g + 1];
        float t = 0.0f;
        for (int idx = s + tid; idx < e; idx += 256) t += q[idx];
#pragma unroll
        for (int m = 32; m >= 1; m >>= 1) t += __shfl_xor(t, m, 64);
        if ((tid & 63) == 0) red[tid >> 6] = t;
        __syncthreads();
        if (tid == 0) {
            const int c = e - s;
            smean[g] = (red[0] + red[1] + red[2] + red[3]) /
                       (float)(c > 0 ? c : 1);
        }
        __syncthreads();
    }

    const float scr = *scr_p;
    const float soft = *soft_p;
    const float soft2 = soft * soft;

    const int i = i0 + ii;
    const int gi = batch32[i];
    const int si = gstart[gi];
    const unsigned span = (unsigned)(gstart[gi + 1] - si);
    const float pix = pos[3 * i + 0];
    const float piy = pos[3 * i + 1];
    const float piz = pos[3 * i + 2];

    const int jlo = gstart[gfirst];
    const int jhi = gstart[glast + 1];

    float acc = 0.0f;
    for (int jt = jlo; jt < jhi; jt += TJ) {
        __syncthreads();
        const int jj = jt + tid;
        float4 v;
        if (jj < jhi) {
            v.x = pos[3 * jj + 0];
            v.y = pos[3 * jj + 1];
            v.z = pos[3 * jj + 2];
            v.w = q[jj] - smean[batch32[jj]];
        } else {
            v.x = v.y = v.z = v.w = 0.0f;
        }
        tile[tid] = v;
        __syncthreads();

        const int cnt = min(TJ, jhi - jt);
        const int base = jt - si;               // hoisted mask arithmetic
        const int ue = min(js * TI + TI, cnt);
        for (int u = js * TI; u < ue; ++u) {
            const float4 p = tile[u];
            const float dx = p.x - pix;
            const float dy = p.y - piy;
            const float dz = p.z - piz;
            float d2 = fmaf(dx, dx, soft2);
            d2 = fmaf(dy, dy, d2);
            d2 = fmaf(dz, dz, d2);
            const float rinv = rsqrtf(d2);
            const float r = d2 * rinv;
            const float e = __expf(-scr * r);
            const float w = ((unsigned)(base + u) < span) ? p.w : 0.0f;
            acc = fmaf(w * e, rinv, acc);
        }
    }
    psum[js * TI + ii] = acc;
    __syncthreads();

    if (tid < TI) {
        float tot = 0.0f;
#pragma unroll
        for (int k = 0; k < JS; ++k) tot += psum[k * TI + tid];
        const float qn = q[i] - smean[gi];
        const float sa = fabsf(soft);
        const float selfk = __expf(-scr * sa) / sa;
        out[i] = 0.5f * qn * (tot - qn * selfk);
    }
}

extern "C" void kernel_launch(void* const* d_in, const int* in_sizes, int n_in,
                              void* d_out, int out_size, void* d_ws, size_t ws_size,
                              hipStream_t stream) {
    const float* x    = (const float*)d_in[0];
    const float* pos  = (const float*)d_in[1];
    // d_in[2] = cell (unused by reference math for nonperiodic path)
    const float* W1   = (const float*)d_in[3];
    const float* b1   = (const float*)d_in[4];
    const float* W2   = (const float*)d_in[5];
    const float* b2   = (const float*)d_in[6];
    const float* scr  = (const float*)d_in[7];
    const float* soft = (const float*)d_in[8];
    const void*  braw = (const void*)d_in[9];

    char* ws = (char*)d_ws;
    int*   batch32 = (int*)(ws + OFF_BATCH32);
    float* q       = (float*)(ws + OFF_Q);
    int*   gstart  = (int*)(ws + OFF_GSTART);
    float* out     = (float*)d_out;

    fused1_kernel<<<2049, 256, 0, stream>>>(x, W1, b1, W2, b2, braw,
                                            batch32, gstart, q);
    pairfin_kernel<<<NATOMS / TI, 256, 0, stream>>>(pos, q, batch32, gstart,
                                                    out, scr, soft);
}